// Round 4
// baseline (11020.546 us; speedup 1.0000x reference)
//
#include <hip/hip_runtime.h>
#include <hip/hip_bf16.h>

// ---------------------------------------------------------------------------
// MySCNN: 3 towers, each = 3 Chebyshev sparse convs (K=5) with leaky-relu.
// Per-batch pipeline (B=2 sequential) to keep workspace ~144 MB:
//   conv1 (4->120):  powers of L on 4 channels, then fused GEMM over K*Cin=20
//   conv2 (120->120): y += Theta_k (L^k t), atomic COO SpMM on 120 channels
//   conv3 (120->4):  z_k = Theta_k x (one pass), then Horner: z_k += L z_{k+1}
// Layout: channel-last (Mp,120) slabs, M padded to x64 (pad rows inert).
// Workspace: [P0][P1][P2][TH1 2560][TH2 76800][TH3 2400], P2 aliases
// conv1 power slots (Mp*20) and conv3 z (5*Mp*4).
// ---------------------------------------------------------------------------

#define LRELU(v) ((v) > 0.f ? (v) : 0.01f * (v))

// ---- per-batch transpose x (4,M) -> SP slot k=0: SP[m*20 + i] --------------
__global__ void k_xpose_in(const float* __restrict__ x, float* __restrict__ SP, int M) {
    int idx = blockIdx.x * blockDim.x + threadIdx.x;
    if (idx >= M * 4) return;
    int i = idx / M, m = idx - i * M;
    SP[(size_t)m * 20 + i] = x[idx];
}

// ---- theta transpose: dst[(k*Cin+i)*Cpad + o] = src[(o*Cin+i)*K + k] -------
__global__ void k_xpose_th(const float* __restrict__ src, float* __restrict__ dst,
                           int Cout, int Cin, int K, int Cpad) {
    int idx = blockIdx.x * blockDim.x + threadIdx.x;
    int tot = K * Cin * Cpad;
    if (idx >= tot) return;
    int o = idx % Cpad;
    int rest = idx / Cpad;
    int i = rest % Cin;
    int k = rest / Cin;
    dst[idx] = (o < Cout) ? src[((size_t)o * Cin + i) * K + k] : 0.f;
}

// ---- conv1 SpMM: SP slot kout += L * SP slot kin (4 channels) --------------
__global__ void k_spmm_sp(const int* __restrict__ rows, const int* __restrict__ cols,
                          const float* __restrict__ vals, int nnz,
                          float* __restrict__ SP, int kin, int kout) {
    int gid = blockIdx.x * blockDim.x + threadIdx.x;
    if (gid >= nnz * 4) return;
    int e = gid >> 2, i = gid & 3;
    float g = vals[e] * SP[(size_t)cols[e] * 20 + kin * 4 + i];
    atomicAdd(&SP[(size_t)rows[e] * 20 + kout * 4 + i], g);
}

// ---- conv3 Horner SpMM: out += L*in, 4 contiguous channels -----------------
__global__ void k_spmm4(const int* __restrict__ rows, const int* __restrict__ cols,
                        const float* __restrict__ vals, int nnz,
                        const float* __restrict__ in, float* __restrict__ out) {
    int gid = blockIdx.x * blockDim.x + threadIdx.x;
    if (gid >= nnz * 4) return;
    int e = gid >> 2, j = gid & 3;
    float g = vals[e] * in[(size_t)cols[e] * 4 + j];
    atomicAdd(&out[(size_t)rows[e] * 4 + j], g);
}

// ---- conv2 SpMM: out += L*in over 120 contiguous channels ------------------
__global__ __launch_bounds__(256) void k_spmm120(
    const int* __restrict__ rows, const int* __restrict__ cols,
    const float* __restrict__ vals, int nnz,
    const float* __restrict__ in, float* __restrict__ out) {
    __shared__ int r_l[16];
    __shared__ int c_l[16];
    __shared__ float v_l[16];
    int e0 = blockIdx.x * 16;
    int tid = threadIdx.x;
    if (tid < 16) {
        int e = e0 + tid;
        if (e < nnz) { r_l[tid] = rows[e]; c_l[tid] = cols[e]; v_l[tid] = vals[e]; }
    }
    __syncthreads();
    int nloc = nnz - e0; if (nloc > 16) nloc = 16;
    int tot = nloc * 120;
    for (int idx = tid; idx < tot; idx += 256) {
        int e = idx / 120;
        int j = idx - e * 120;
        float g = v_l[e] * in[(size_t)c_l[e] * 120 + j];
        atomicAdd(&out[(size_t)r_l[e] * 120 + j], g);
    }
}

// ---- conv1 GEMM: y[m,o] = lrelu(bias[o] + sum_kk th[kk][o]*SP[m,kk]), kk<20
__global__ __launch_bounds__(256) void k_gemm_c1(
    const float* __restrict__ SP, const float* __restrict__ tht, // (20,128)
    const float* __restrict__ bias, float* __restrict__ y) {
    __shared__ float in_lds[64 * 20];
    __shared__ float th_lds[20 * 128];
    int mb0 = blockIdx.x * 64;
    int tid = threadIdx.x;
    {
        const float4* s = (const float4*)tht;
        float4* d = (float4*)th_lds;
        for (int t = tid; t < 640; t += 256) d[t] = s[t];
    }
    {
        const float4* s = (const float4*)(SP + (size_t)mb0 * 20);
        float4* d = (float4*)in_lds;
        for (int t = tid; t < 320; t += 256) d[t] = s[t];
    }
    __syncthreads();
    int og = tid & 15, mbg = tid >> 4;
    int o = og * 8;
    float acc[4][8];
#pragma unroll
    for (int r = 0; r < 4; ++r)
#pragma unroll
        for (int c = 0; c < 8; ++c) acc[r][c] = 0.f;
#pragma unroll
    for (int kk = 0; kk < 20; ++kk) {
        float a0 = in_lds[(mbg * 4 + 0) * 20 + kk];
        float a1 = in_lds[(mbg * 4 + 1) * 20 + kk];
        float a2 = in_lds[(mbg * 4 + 2) * 20 + kk];
        float a3 = in_lds[(mbg * 4 + 3) * 20 + kk];
        float4 t0 = *(const float4*)&th_lds[kk * 128 + o];
        float4 t1 = *(const float4*)&th_lds[kk * 128 + o + 4];
        float tv[8] = {t0.x, t0.y, t0.z, t0.w, t1.x, t1.y, t1.z, t1.w};
#pragma unroll
        for (int c = 0; c < 8; ++c) {
            acc[0][c] += a0 * tv[c];
            acc[1][c] += a1 * tv[c];
            acc[2][c] += a2 * tv[c];
            acc[3][c] += a3 * tv[c];
        }
    }
    if (o < 120) {
#pragma unroll
        for (int r = 0; r < 4; ++r) {
            int mb = mb0 + mbg * 4 + r;
            float* yp = y + (size_t)mb * 120 + o;
#pragma unroll
            for (int c = 0; c < 8; ++c) {
                float v = acc[r][c] + bias[o + c];
                yp[c] = LRELU(v);
            }
        }
    }
}

// ---- conv2 GEMM: y (+)= tht_k^T . tin  (Cin=120 -> Cout=120) ---------------
template <int INIT, int FINAL>
__global__ __launch_bounds__(256) void k_gemm120(
    const float* __restrict__ tin,  // (Mp,120)
    const float* __restrict__ tht,  // (120,128) slice for this k
    const float* __restrict__ bias, // 120 (FINAL only)
    float* __restrict__ y) {        // (Mp,120)
    __shared__ float in_lds[64 * 124];
    __shared__ float th_lds[120 * 128];
    int mb0 = blockIdx.x * 64;
    int tid = threadIdx.x;
    {
        const float4* s = (const float4*)tht;
        float4* d = (float4*)th_lds;
#pragma unroll
        for (int t = 0; t < 15; ++t) d[tid + t * 256] = s[tid + t * 256];
    }
    {
        const float4* s = (const float4*)(tin + (size_t)mb0 * 120);
        for (int t = tid; t < 1920; t += 256) {
            int row = t / 30, q = t - row * 30;
            *(float4*)&in_lds[row * 124 + q * 4] = s[t];
        }
    }
    __syncthreads();
    int og = tid & 15, mbg = tid >> 4;
    int o = og * 8;
    float acc[4][8];
#pragma unroll
    for (int r = 0; r < 4; ++r)
#pragma unroll
        for (int c = 0; c < 8; ++c) acc[r][c] = 0.f;
#pragma unroll 4
    for (int i = 0; i < 120; ++i) {
        float a0 = in_lds[(mbg * 4 + 0) * 124 + i];
        float a1 = in_lds[(mbg * 4 + 1) * 124 + i];
        float a2 = in_lds[(mbg * 4 + 2) * 124 + i];
        float a3 = in_lds[(mbg * 4 + 3) * 124 + i];
        float4 t0 = *(const float4*)&th_lds[i * 128 + o];
        float4 t1 = *(const float4*)&th_lds[i * 128 + o + 4];
        float tv[8] = {t0.x, t0.y, t0.z, t0.w, t1.x, t1.y, t1.z, t1.w};
#pragma unroll
        for (int c = 0; c < 8; ++c) {
            acc[0][c] += a0 * tv[c];
            acc[1][c] += a1 * tv[c];
            acc[2][c] += a2 * tv[c];
            acc[3][c] += a3 * tv[c];
        }
    }
    if (o < 120) {
#pragma unroll
        for (int r = 0; r < 4; ++r) {
            int mb = mb0 + mbg * 4 + r;
            float* yp = y + (size_t)mb * 120 + o;
#pragma unroll
            for (int c = 0; c < 8; ++c) {
                float v = acc[r][c];
                if (!INIT) v += yp[c];
                if (FINAL) { v += bias[o + c]; v = LRELU(v); }
                yp[c] = v;
            }
        }
    }
}

// ---- conv3 z-pass: z_k[m,o] = sum_i th[k][i][o]*x[m,i]; z_0 += bias --------
__global__ __launch_bounds__(256) void k_zconv3(
    const float* __restrict__ x,   // (Mp,120)
    const float* __restrict__ tht, // (5*120*4) [k][i][o]
    const float* __restrict__ bias,// 4
    float* __restrict__ z, int Mp) {
    __shared__ float x_lds[64 * 124];
    __shared__ float th_lds[2400];
    int mb0 = blockIdx.x * 64;
    int tid = threadIdx.x;
    for (int t = tid; t < 600; t += 256) ((float4*)th_lds)[t] = ((const float4*)tht)[t];
    {
        const float4* s = (const float4*)(x + (size_t)mb0 * 120);
        for (int t = tid; t < 1920; t += 256) {
            int row = t / 30, q = t - row * 30;
            *(float4*)&x_lds[row * 124 + q * 4] = s[t];
        }
    }
    __syncthreads();
    int o = tid & 3, mbl = tid >> 2;
    float acc[5] = {0.f, 0.f, 0.f, 0.f, 0.f};
    for (int i = 0; i < 120; ++i) {
        float xv = x_lds[mbl * 124 + i];
#pragma unroll
        for (int k = 0; k < 5; ++k) acc[k] += xv * th_lds[(k * 120 + i) * 4 + o];
    }
    acc[0] += bias[o];
    int mb = mb0 + mbl;
    size_t slice = (size_t)Mp * 4;
#pragma unroll
    for (int k = 0; k < 5; ++k) z[k * slice + (size_t)mb * 4 + o] = acc[k];
}

// ---- final per-batch transpose: dout[o*M + m] = z0[m*4 + o] ----------------
__global__ void k_xpose_out(const float* __restrict__ z0, float* __restrict__ dout, int M) {
    int idx = blockIdx.x * blockDim.x + threadIdx.x;
    if (idx >= M * 4) return;
    int o = idx / M, m = idx - o * M;
    dout[idx] = z0[(size_t)m * 4 + o];
}

static inline int cdiv(long a, long b) { return (int)((a + b - 1) / b); }

extern "C" void kernel_launch(void* const* d_in, const int* in_sizes, int n_in,
                              void* d_out, int out_size, void* d_ws, size_t ws_size,
                              hipStream_t stream) {
    const int MSa[3]  = {40000, 100000, 60000};
    const int NNZa[3] = {400000, 1000000, 600000};
    const float* xs[3] = {(const float*)d_in[0], (const float*)d_in[4], (const float*)d_in[8]};
    const int* rr[3]   = {(const int*)d_in[1], (const int*)d_in[5], (const int*)d_in[9]};
    const int* cc[3]   = {(const int*)d_in[2], (const int*)d_in[6], (const int*)d_in[10]};
    const float* vv[3] = {(const float*)d_in[3], (const float*)d_in[7], (const float*)d_in[11]};

    float* out = (float*)d_out;
    size_t out_off = 0;

    for (int t = 0; t < 3; ++t) {
        const int M = MSa[t], nnz = NNZa[t];
        const int Mp = ((M + 63) / 64) * 64;
        const size_t slab = (size_t)Mp * 120;   // floats

        const float* th1 = (const float*)d_in[12 + t * 6 + 0];
        const float* b1  = (const float*)d_in[12 + t * 6 + 1];
        const float* th2 = (const float*)d_in[12 + t * 6 + 2];
        const float* b2  = (const float*)d_in[12 + t * 6 + 3];
        const float* th3 = (const float*)d_in[12 + t * 6 + 4];
        const float* b3  = (const float*)d_in[12 + t * 6 + 5];

        float* P0  = (float*)d_ws;
        float* P1  = P0 + slab;
        float* P2  = P1 + slab;          // aliases conv1 powers (Mp*20) & conv3 z (Mp*20)
        float* TH1 = P2 + slab;          // 2560 floats
        float* TH2 = TH1 + 2560;         // 76800 floats
        float* TH3 = TH2 + 76800;        // 2400 floats

        k_xpose_th<<<cdiv(2560, 256), 256, 0, stream>>>(th1, TH1, 120, 4, 5, 128);
        k_xpose_th<<<cdiv(76800, 256), 256, 0, stream>>>(th2, TH2, 120, 120, 5, 128);
        k_xpose_th<<<cdiv(2400, 256), 256, 0, stream>>>(th3, TH3, 4, 120, 5, 4);

        for (int b = 0; b < 2; ++b) {
            const float* xb = xs[t] + (size_t)b * 4 * M;
            float* outb = out + out_off + (size_t)b * 4 * M;

            // ---- conv1: powers of L on 4 channels in P2, fused GEMM ----
            hipMemsetAsync(P2, 0, (size_t)Mp * 20 * sizeof(float), stream);
            k_xpose_in<<<cdiv((long)M * 4, 256), 256, 0, stream>>>(xb, P2, M);
            for (int k = 1; k <= 4; ++k)
                k_spmm_sp<<<cdiv((long)nnz * 4, 256), 256, 0, stream>>>(
                    rr[t], cc[t], vv[t], nnz, P2, k - 1, k);
            k_gemm_c1<<<Mp / 64, 256, 0, stream>>>(P2, TH1, b1, P0);

            // ---- conv2: y(P1) accumulated over k; ping-pong P0<->P2 ----
            k_gemm120<1, 0><<<Mp / 64, 256, 0, stream>>>(P0, TH2, nullptr, P1);
            {
                float* tsrc = P0;
                float* tdst = P2;
                for (int k = 1; k <= 4; ++k) {
                    hipMemsetAsync(tdst, 0, slab * sizeof(float), stream);
                    k_spmm120<<<cdiv(nnz, 16), 256, 0, stream>>>(
                        rr[t], cc[t], vv[t], nnz, tsrc, tdst);
                    if (k < 4)
                        k_gemm120<0, 0><<<Mp / 64, 256, 0, stream>>>(
                            tdst, TH2 + (size_t)k * 15360, nullptr, P1);
                    else
                        k_gemm120<0, 1><<<Mp / 64, 256, 0, stream>>>(
                            tdst, TH2 + (size_t)4 * 15360, b2, P1);
                    float* tmp = tsrc; tsrc = tdst; tdst = tmp;
                }
            }

            // ---- conv3: z_k = Theta_k x in P2, then in-place Horner ----
            k_zconv3<<<Mp / 64, 256, 0, stream>>>(P1, TH3, b3, P2, Mp);
            for (int k = 3; k >= 0; --k)
                k_spmm4<<<cdiv((long)nnz * 4, 256), 256, 0, stream>>>(
                    rr[t], cc[t], vv[t], nnz,
                    P2 + (size_t)(k + 1) * Mp * 4, P2 + (size_t)k * Mp * 4);

            k_xpose_out<<<cdiv((long)M * 4, 256), 256, 0, stream>>>(P2, outb, M);
        }
        out_off += (size_t)M * 8;
    }
    (void)in_sizes; (void)n_in; (void)out_size; (void)ws_size;
}

// Round 6
// 4738.474 us; speedup vs baseline: 2.3258x; 2.3258x over previous
//
#include <hip/hip_runtime.h>
#include <hip/hip_bf16.h>

// ---------------------------------------------------------------------------
// MySCNN: 3 towers, each = 3 Chebyshev sparse convs (K=5) with leaky-relu.
// Round 4->5: atomic COO SpMM replaced by CSR (row-sorted) gather SpMM.
//   - CSR built once per tower in ws (hist -> 2-level scan -> scatter)
//   - k_csr120: one wave per row, register accumulate, 1 store per row
//   - conv1 powers / conv3 Horner: thread-per-(row,ch) CSR, non-atomic
//   - all big memsets eliminated (overwrite semantics)
// Pipeline per tower (B=2 sequential): conv1 input-side powers (4ch) ->
// GEMM(K*Cin=20); conv2 alternating CSR-SpMM(120ch)/GEMM accumulate;
// conv3 output-side Horner (z_k = Theta_k x, z_k += L z_{k+1}).
// Layout: channel-last slabs (Mp,120); pad rows [M,Mp) inert (finite garbage).
// ---------------------------------------------------------------------------

#define LRELU(v) ((v) > 0.f ? (v) : 0.01f * (v))

// ---- per-batch transpose x (4,M) -> SP slot k=0: SP[m*20 + i] --------------
__global__ void k_xpose_in(const float* __restrict__ x, float* __restrict__ SP, int M) {
    int idx = blockIdx.x * blockDim.x + threadIdx.x;
    if (idx >= M * 4) return;
    int i = idx / M, m = idx - i * M;
    SP[(size_t)m * 20 + i] = x[idx];
}

// ---- theta transpose: dst[(k*Cin+i)*Cpad + o] = src[(o*Cin+i)*K + k] -------
__global__ void k_xpose_th(const float* __restrict__ src, float* __restrict__ dst,
                           int Cout, int Cin, int K, int Cpad) {
    int idx = blockIdx.x * blockDim.x + threadIdx.x;
    int tot = K * Cin * Cpad;
    if (idx >= tot) return;
    int o = idx % Cpad;
    int rest = idx / Cpad;
    int i = rest % Cin;
    int k = rest / Cin;
    dst[idx] = (o < Cout) ? src[((size_t)o * Cin + i) * K + k] : 0.f;
}

// ============================ CSR build =====================================
__global__ void k_hist(const int* __restrict__ rows, int nnz, int* __restrict__ cnt) {
    int e = blockIdx.x * blockDim.x + threadIdx.x;
    if (e < nnz) atomicAdd(&cnt[rows[e]], 1);
}

// block-local exclusive scan of cnt -> rp; block totals -> part
__global__ __launch_bounds__(256) void k_scan1(const int* __restrict__ cnt, int M,
                                               int* __restrict__ rp, int* __restrict__ part) {
    __shared__ int lds[256];
    int tid = threadIdx.x;
    int i = blockIdx.x * 256 + tid;
    int v = (i < M) ? cnt[i] : 0;
    lds[tid] = v;
    __syncthreads();
    for (int off = 1; off < 256; off <<= 1) {
        int t = (tid >= off) ? lds[tid - off] : 0;
        __syncthreads();
        lds[tid] += t;
        __syncthreads();
    }
    if (i < M) rp[i] = lds[tid] - v;           // exclusive within block
    if (tid == 255) part[blockIdx.x] = lds[255];
}

// single-block exclusive scan of block partials (npart <= 512)
__global__ __launch_bounds__(512) void k_scan2(int* __restrict__ part, int npart) {
    __shared__ int lds[512];
    int tid = threadIdx.x;
    int v = (tid < npart) ? part[tid] : 0;
    lds[tid] = v;
    __syncthreads();
    for (int off = 1; off < 512; off <<= 1) {
        int t = (tid >= off) ? lds[tid - off] : 0;
        __syncthreads();
        lds[tid] += t;
        __syncthreads();
    }
    if (tid < npart) part[tid] = lds[tid] - v;  // exclusive
}

// add block offsets; produce final rp and mutable cursor; rp[M] = nnz
__global__ void k_scan3(int* __restrict__ rp, int* __restrict__ cur,
                        const int* __restrict__ part, int M, int nnz) {
    int i = blockIdx.x * 256 + threadIdx.x;
    if (i < M) {
        int r = rp[i] + part[blockIdx.x];
        rp[i] = r;
        cur[i] = r;
    }
    if (i == 0) rp[M] = nnz;
}

__global__ void k_scatter(const int* __restrict__ rows, const int* __restrict__ cols,
                          const float* __restrict__ vals, int nnz,
                          int* __restrict__ cur, int* __restrict__ col2,
                          float* __restrict__ val2) {
    int e = blockIdx.x * blockDim.x + threadIdx.x;
    if (e >= nnz) return;
    int pos = atomicAdd(&cur[rows[e]], 1);
    col2[pos] = cols[e];
    val2[pos] = vals[e];
}

// ============================ CSR SpMM ======================================
// conv2: one wave per row, 120 channels as float2 per lane (lanes 0..59)
__global__ __launch_bounds__(256) void k_csr120(
    const int* __restrict__ rp, const int* __restrict__ col2,
    const float* __restrict__ val2,
    const float* __restrict__ in, float* __restrict__ out, int M) {
    int wid = (blockIdx.x * 256 + threadIdx.x) >> 6;   // row
    if (wid >= M) return;
    int lane = threadIdx.x & 63;
    int e0 = rp[wid], e1 = rp[wid + 1];
    int c = lane * 2;
    bool act = c < 120;
    float ax = 0.f, ay = 0.f;
    for (int e = e0; e < e1; ++e) {
        float v = val2[e];
        int col = col2[e];
        if (act) {
            float2 xv = *(const float2*)&in[(size_t)col * 120 + c];
            ax += v * xv.x;
            ay += v * xv.y;
        }
    }
    if (act) {
        float2 r; r.x = ax; r.y = ay;
        *(float2*)&out[(size_t)wid * 120 + c] = r;
    }
}

// conv1 powers: SP slot kout = L * SP slot kin (4 strided channels)
__global__ void k_csr_sp(const int* __restrict__ rp, const int* __restrict__ col2,
                         const float* __restrict__ val2,
                         float* __restrict__ SP, int M, int kin, int kout) {
    int t = blockIdx.x * blockDim.x + threadIdx.x;
    if (t >= M * 4) return;
    int row = t >> 2, i = t & 3;
    int e0 = rp[row], e1 = rp[row + 1];
    float acc = 0.f;
    for (int e = e0; e < e1; ++e)
        acc += val2[e] * SP[(size_t)col2[e] * 20 + kin * 4 + i];
    SP[(size_t)row * 20 + kout * 4 + i] = acc;
}

// conv3 Horner: out(z_k) += L * in(z_{k+1}), 4 contiguous channels
__global__ void k_csr4(const int* __restrict__ rp, const int* __restrict__ col2,
                       const float* __restrict__ val2,
                       const float* __restrict__ in, float* __restrict__ out, int M) {
    int t = blockIdx.x * blockDim.x + threadIdx.x;
    if (t >= M * 4) return;
    int row = t >> 2, j = t & 3;
    int e0 = rp[row], e1 = rp[row + 1];
    float acc = out[(size_t)row * 4 + j];
    for (int e = e0; e < e1; ++e)
        acc += val2[e] * in[(size_t)col2[e] * 4 + j];
    out[(size_t)row * 4 + j] = acc;
}

// ============================ dense mixing ==================================
// conv1 GEMM: y[m,o] = lrelu(bias[o] + sum_kk th[kk][o]*SP[m,kk]), kk<20
__global__ __launch_bounds__(256) void k_gemm_c1(
    const float* __restrict__ SP, const float* __restrict__ tht, // (20,128)
    const float* __restrict__ bias, float* __restrict__ y) {
    __shared__ float in_lds[64 * 20];
    __shared__ float th_lds[20 * 128];
    int mb0 = blockIdx.x * 64;
    int tid = threadIdx.x;
    {
        const float4* s = (const float4*)tht;
        float4* d = (float4*)th_lds;
        for (int t = tid; t < 640; t += 256) d[t] = s[t];
    }
    {
        const float4* s = (const float4*)(SP + (size_t)mb0 * 20);
        float4* d = (float4*)in_lds;
        for (int t = tid; t < 320; t += 256) d[t] = s[t];
    }
    __syncthreads();
    int og = tid & 15, mbg = tid >> 4;
    int o = og * 8;
    float acc[4][8];
#pragma unroll
    for (int r = 0; r < 4; ++r)
#pragma unroll
        for (int c = 0; c < 8; ++c) acc[r][c] = 0.f;
#pragma unroll
    for (int kk = 0; kk < 20; ++kk) {
        float a0 = in_lds[(mbg * 4 + 0) * 20 + kk];
        float a1 = in_lds[(mbg * 4 + 1) * 20 + kk];
        float a2 = in_lds[(mbg * 4 + 2) * 20 + kk];
        float a3 = in_lds[(mbg * 4 + 3) * 20 + kk];
        float4 t0 = *(const float4*)&th_lds[kk * 128 + o];
        float4 t1 = *(const float4*)&th_lds[kk * 128 + o + 4];
        float tv[8] = {t0.x, t0.y, t0.z, t0.w, t1.x, t1.y, t1.z, t1.w};
#pragma unroll
        for (int c = 0; c < 8; ++c) {
            acc[0][c] += a0 * tv[c];
            acc[1][c] += a1 * tv[c];
            acc[2][c] += a2 * tv[c];
            acc[3][c] += a3 * tv[c];
        }
    }
    if (o < 120) {
#pragma unroll
        for (int r = 0; r < 4; ++r) {
            int mb = mb0 + mbg * 4 + r;
            float* yp = y + (size_t)mb * 120 + o;
#pragma unroll
            for (int c = 0; c < 8; ++c) {
                float v = acc[r][c] + bias[o + c];
                yp[c] = LRELU(v);
            }
        }
    }
}

// conv2 GEMM: y (+)= tht_k^T . tin  (Cin=120 -> Cout=120)
template <int INIT, int FINAL>
__global__ __launch_bounds__(256) void k_gemm120(
    const float* __restrict__ tin,  // (Mp,120)
    const float* __restrict__ tht,  // (120,128) slice for this k
    const float* __restrict__ bias, // 120 (FINAL only)
    float* __restrict__ y) {        // (Mp,120)
    __shared__ float in_lds[64 * 124];
    __shared__ float th_lds[120 * 128];
    int mb0 = blockIdx.x * 64;
    int tid = threadIdx.x;
    {
        const float4* s = (const float4*)tht;
        float4* d = (float4*)th_lds;
#pragma unroll
        for (int t = 0; t < 15; ++t) d[tid + t * 256] = s[tid + t * 256];
    }
    {
        const float4* s = (const float4*)(tin + (size_t)mb0 * 120);
        for (int t = tid; t < 1920; t += 256) {
            int row = t / 30, q = t - row * 30;
            *(float4*)&in_lds[row * 124 + q * 4] = s[t];
        }
    }
    __syncthreads();
    int og = tid & 15, mbg = tid >> 4;
    int o = og * 8;
    float acc[4][8];
#pragma unroll
    for (int r = 0; r < 4; ++r)
#pragma unroll
        for (int c = 0; c < 8; ++c) acc[r][c] = 0.f;
#pragma unroll 4
    for (int i = 0; i < 120; ++i) {
        float a0 = in_lds[(mbg * 4 + 0) * 124 + i];
        float a1 = in_lds[(mbg * 4 + 1) * 124 + i];
        float a2 = in_lds[(mbg * 4 + 2) * 124 + i];
        float a3 = in_lds[(mbg * 4 + 3) * 124 + i];
        float4 t0 = *(const float4*)&th_lds[i * 128 + o];
        float4 t1 = *(const float4*)&th_lds[i * 128 + o + 4];
        float tv[8] = {t0.x, t0.y, t0.z, t0.w, t1.x, t1.y, t1.z, t1.w};
#pragma unroll
        for (int c = 0; c < 8; ++c) {
            acc[0][c] += a0 * tv[c];
            acc[1][c] += a1 * tv[c];
            acc[2][c] += a2 * tv[c];
            acc[3][c] += a3 * tv[c];
        }
    }
    if (o < 120) {
#pragma unroll
        for (int r = 0; r < 4; ++r) {
            int mb = mb0 + mbg * 4 + r;
            float* yp = y + (size_t)mb * 120 + o;
#pragma unroll
            for (int c = 0; c < 8; ++c) {
                float v = acc[r][c];
                if (!INIT) v += yp[c];
                if (FINAL) { v += bias[o + c]; v = LRELU(v); }
                yp[c] = v;
            }
        }
    }
}

// conv3 z-pass: z_k[m,o] = sum_i th[k][i][o]*x[m,i]; z_0 += bias
__global__ __launch_bounds__(256) void k_zconv3(
    const float* __restrict__ x,   // (Mp,120)
    const float* __restrict__ tht, // (5*120*4) [k][i][o]
    const float* __restrict__ bias,// 4
    float* __restrict__ z, int Mp) {
    __shared__ float x_lds[64 * 124];
    __shared__ float th_lds[2400];
    int mb0 = blockIdx.x * 64;
    int tid = threadIdx.x;
    for (int t = tid; t < 600; t += 256) ((float4*)th_lds)[t] = ((const float4*)tht)[t];
    {
        const float4* s = (const float4*)(x + (size_t)mb0 * 120);
        for (int t = tid; t < 1920; t += 256) {
            int row = t / 30, q = t - row * 30;
            *(float4*)&x_lds[row * 124 + q * 4] = s[t];
        }
    }
    __syncthreads();
    int o = tid & 3, mbl = tid >> 2;
    float acc[5] = {0.f, 0.f, 0.f, 0.f, 0.f};
    for (int i = 0; i < 120; ++i) {
        float xv = x_lds[mbl * 124 + i];
#pragma unroll
        for (int k = 0; k < 5; ++k) acc[k] += xv * th_lds[(k * 120 + i) * 4 + o];
    }
    acc[0] += bias[o];
    int mb = mb0 + mbl;
    size_t slice = (size_t)Mp * 4;
#pragma unroll
    for (int k = 0; k < 5; ++k) z[k * slice + (size_t)mb * 4 + o] = acc[k];
}

// ---- final per-batch transpose: dout[o*M + m] = z0[m*4 + o] ----------------
__global__ void k_xpose_out(const float* __restrict__ z0, float* __restrict__ dout, int M) {
    int idx = blockIdx.x * blockDim.x + threadIdx.x;
    if (idx >= M * 4) return;
    int o = idx / M, m = idx - o * M;
    dout[idx] = z0[(size_t)m * 4 + o];
}

static inline int cdiv(long a, long b) { return (int)((a + b - 1) / b); }

extern "C" void kernel_launch(void* const* d_in, const int* in_sizes, int n_in,
                              void* d_out, int out_size, void* d_ws, size_t ws_size,
                              hipStream_t stream) {
    const int MSa[3]  = {40000, 100000, 60000};
    const int NNZa[3] = {400000, 1000000, 600000};
    const float* xs[3] = {(const float*)d_in[0], (const float*)d_in[4], (const float*)d_in[8]};
    const int* rr[3]   = {(const int*)d_in[1], (const int*)d_in[5], (const int*)d_in[9]};
    const int* cc[3]   = {(const int*)d_in[2], (const int*)d_in[6], (const int*)d_in[10]};
    const float* vv[3] = {(const float*)d_in[3], (const float*)d_in[7], (const float*)d_in[11]};

    float* out = (float*)d_out;
    size_t out_off = 0;

    for (int t = 0; t < 3; ++t) {
        const int M = MSa[t], nnz = NNZa[t];
        const int Mp = ((M + 63) / 64) * 64;
        const size_t slab = (size_t)Mp * 120;   // floats

        const float* th1 = (const float*)d_in[12 + t * 6 + 0];
        const float* b1  = (const float*)d_in[12 + t * 6 + 1];
        const float* th2 = (const float*)d_in[12 + t * 6 + 2];
        const float* b2  = (const float*)d_in[12 + t * 6 + 3];
        const float* th3 = (const float*)d_in[12 + t * 6 + 4];
        const float* b3  = (const float*)d_in[12 + t * 6 + 5];

        float* P0  = (float*)d_ws;
        float* P1  = P0 + slab;
        float* P2  = P1 + slab;          // aliases conv1 powers (Mp*20) & conv3 z (Mp*20)
        float* TH1 = P2 + slab;          // 2560 floats
        float* TH2 = TH1 + 2560;         // 76800 floats
        float* TH3 = TH2 + 76800;        // 2400 floats
        int*   RP   = (int*)(TH3 + 2400);   // M+1
        int*   CUR  = RP + (Mp + 64);       // M  (also used as histogram cnt)
        int*   PART = CUR + Mp;             // <=512 block partials
        int*   COL2 = PART + 512;           // nnz
        float* VAL2 = (float*)(COL2 + nnz); // nnz

        // ---- theta repacks ----
        k_xpose_th<<<cdiv(2560, 256), 256, 0, stream>>>(th1, TH1, 120, 4, 5, 128);
        k_xpose_th<<<cdiv(76800, 256), 256, 0, stream>>>(th2, TH2, 120, 120, 5, 128);
        k_xpose_th<<<cdiv(2400, 256), 256, 0, stream>>>(th3, TH3, 4, 120, 5, 4);

        // ---- CSR build (once per tower) ----
        const int nblkM = cdiv(M, 256);     // <= 391
        hipMemsetAsync(CUR, 0, (size_t)M * sizeof(int), stream);
        k_hist<<<cdiv(nnz, 256), 256, 0, stream>>>(rr[t], nnz, CUR);
        k_scan1<<<nblkM, 256, 0, stream>>>(CUR, M, RP, PART);
        k_scan2<<<1, 512, 0, stream>>>(PART, nblkM);
        k_scan3<<<nblkM, 256, 0, stream>>>(RP, CUR, PART, M, nnz);
        k_scatter<<<cdiv(nnz, 256), 256, 0, stream>>>(rr[t], cc[t], vv[t], nnz, CUR, COL2, VAL2);

        for (int b = 0; b < 2; ++b) {
            const float* xb = xs[t] + (size_t)b * 4 * M;
            float* outb = out + out_off + (size_t)b * 4 * M;

            // ---- conv1: powers of L on 4 channels in P2, fused GEMM ----
            k_xpose_in<<<cdiv((long)M * 4, 256), 256, 0, stream>>>(xb, P2, M);
            for (int k = 1; k <= 4; ++k)
                k_csr_sp<<<cdiv((long)M * 4, 256), 256, 0, stream>>>(
                    RP, COL2, VAL2, P2, M, k - 1, k);
            k_gemm_c1<<<Mp / 64, 256, 0, stream>>>(P2, TH1, b1, P0);

            // ---- conv2: y(P1) accumulated over k; ping-pong P0<->P2 ----
            k_gemm120<1, 0><<<Mp / 64, 256, 0, stream>>>(P0, TH2, nullptr, P1);
            {
                float* tsrc = P0;
                float* tdst = P2;
                for (int k = 1; k <= 4; ++k) {
                    k_csr120<<<cdiv(M, 4), 256, 0, stream>>>(
                        RP, COL2, VAL2, tsrc, tdst, M);
                    if (k < 4)
                        k_gemm120<0, 0><<<Mp / 64, 256, 0, stream>>>(
                            tdst, TH2 + (size_t)k * 15360, nullptr, P1);
                    else
                        k_gemm120<0, 1><<<Mp / 64, 256, 0, stream>>>(
                            tdst, TH2 + (size_t)4 * 15360, b2, P1);
                    float* tmp = tsrc; tsrc = tdst; tdst = tmp;
                }
            }

            // ---- conv3: z_k = Theta_k x in P2, then in-place Horner ----
            k_zconv3<<<Mp / 64, 256, 0, stream>>>(P1, TH3, b3, P2, Mp);
            for (int k = 3; k >= 0; --k)
                k_csr4<<<cdiv((long)M * 4, 256), 256, 0, stream>>>(
                    RP, COL2, VAL2,
                    P2 + (size_t)(k + 1) * Mp * 4, P2 + (size_t)k * Mp * 4, M);

            k_xpose_out<<<cdiv((long)M * 4, 256), 256, 0, stream>>>(P2, outb, M);
        }
        out_off += (size_t)M * 8;
    }
    (void)in_sizes; (void)n_in; (void)out_size; (void)ws_size;
}